// Round 8
// baseline (367.420 us; speedup 1.0000x reference)
//
#include <hip/hip_runtime.h>
#include <hip/hip_bf16.h>

// CLIPAttention (B=16,T=1024,E=1024,H=16,DH=64) with 2D RoPE, bf16 MFMA path.
#define B_  16
#define T_  1024
#define E_  1024
#define H_  16
#define DH_ 64

typedef short s16x8 __attribute__((ext_vector_type(8)));   // 8 bf16 = 4 VGPRs (MFMA A/B frag)
typedef float f32x4 __attribute__((ext_vector_type(4)));   // MFMA C/D frag
typedef unsigned short u16x4 __attribute__((ext_vector_type(4)));  // 4 bf16 = 8B

__device__ __forceinline__ void async_cp16(const void* g, void* l) {
  __builtin_amdgcn_global_load_lds(
      (__attribute__((address_space(1))) unsigned int*)(g),
      (__attribute__((address_space(3))) unsigned int*)(l), 16, 0, 0);
}

__device__ __forceinline__ s16x8 frag8(const void* p) { return *(const s16x8*)p; }

__device__ __forceinline__ float fexp2(float x) {
#if __has_builtin(__builtin_amdgcn_exp2f)
  return __builtin_amdgcn_exp2f(x);
#else
  return exp2f(x);
#endif
}

__device__ __forceinline__ unsigned short f2bu(float x) {
  __hip_bfloat16 h = __float2bfloat16(x);
  return *reinterpret_cast<unsigned short*>(&h);
}

// ---------------- single fused cast fp32 -> bf16 (X + 4 weight mats) ----------------
// X rows remapped so XCD x casts rows [x*2048, (x+1)*2048) (matches GEMM bm pinning).
__global__ __launch_bounds__(256) void cast_all(const float* __restrict__ X,
                                                const float* __restrict__ Wq,
                                                const float* __restrict__ Wk,
                                                const float* __restrict__ Wv,
                                                const float* __restrict__ Wo,
                                                __hip_bfloat16* __restrict__ Xb,
                                                __hip_bfloat16* __restrict__ Wqkvb,
                                                __hip_bfloat16* __restrict__ Wob) {
  const int bid = blockIdx.x;
  const float* src;
  __hip_bfloat16* dst;
  int i;
  if (bid < 16384) {
    src = X; dst = Xb;
    i = ((bid & 7) * 2048 + (bid >> 3)) * 256 + threadIdx.x;
  } else {
    const int wb = bid - 16384;
    const int w = wb >> 10;
    src = (w == 0) ? Wq : (w == 1) ? Wk : (w == 2) ? Wv : Wo;
    dst = (w == 3) ? Wob : Wqkvb + (size_t)w * 1048576;
    i = (wb & 1023) * 256 + threadIdx.x;
  }
  float4 v = ((const float4*)src)[i];
  u16x4 pk = {f2bu(v.x), f2bu(v.y), f2bu(v.z), f2bu(v.w)};
  *(u16x4*)(dst + (size_t)i * 4) = pk;
}

// ======================================================================
// R8 GEMM core: 256x128 tile, BK=32, TRIPLE-buffered LDS (3 x 24KB = 72KB
// -> 2 blocks/CU), 8 waves (4M x 2N, per-wave 64x64 -> acc=64 regs -> 4
// waves/SIMD), ONE phase per K-tile (2 barriers/tile, 64 total).
// LDS layout per buf: A 256x32 (16KB, rows 64B) then B 128x32 (8KB).
// Swizzle (64B rows, 4 x 16B slots): slot s of row R holds k-group
// s ^ ((R>>1)&3); applied on the global source (gsw) and on frag reads
// (swk) with the same involution -> correctness by construction; bank
// spread 2-way (free). Staging: A = 16 chunks (2/wave), B = 8 (1/wave).
// Prefetch: tile j issues (j+2) -> buf (j+2)%3, whose last reads retired
// at the end-of-(j-1) barrier -> no read/write overlap, no R4-class race.
// vmcnt trace (3 loads/wave/tile): steady end-of-j queue = [(j+1):3,
// (j+2):3] -> vmcnt(3); j=30,31 -> vmcnt(0). Issue->consume = 2 phases.
// ======================================================================
#define T3_ISSUE(SRC_, LOFF_, D_, KT2_, NCH_)                                   \
  {                                                                             \
    _Pragma("unroll") for (int u_ = 0; u_ < (NCH_); ++u_) {                     \
      const int ch_ = u_ * 8 + wave;                                            \
      async_cp16(SRC_ + (size_t)(ch_ * 16) * 2048 + (KT2_)*64,                  \
                 smem + (D_)*24576 + (LOFF_) + ch_ * 1024);                     \
    }                                                                           \
  }

#define T3_READ(D_)                                                             \
  {                                                                             \
    _Pragma("unroll") for (int i_ = 0; i_ < 4; ++i_)                            \
      af[i_] = frag8(smem + (D_)*24576 + (wrow * 64 + i_ * 16 + col) * 64 + swk); \
    _Pragma("unroll") for (int j_ = 0; j_ < 4; ++j_)                            \
      bf[j_] = frag8(smem + (D_)*24576 + 16384 + (wcol * 64 + j_ * 16 + col) * 64 + swk); \
  }

#define T3_MFMA()                                                               \
  {                                                                             \
    __builtin_amdgcn_s_setprio(1);                                              \
    _Pragma("unroll") for (int i_ = 0; i_ < 4; ++i_)                            \
      _Pragma("unroll") for (int j_ = 0; j_ < 4; ++j_)                          \
        acc[i_][j_] = __builtin_amdgcn_mfma_f32_16x16x32_bf16(af[i_], bf[j_], acc[i_][j_], 0, 0, 0); \
    __builtin_amdgcn_s_setprio(0);                                              \
  }

#define T3_KTILE(BUF_, GI_, IBUF_, KT2_, W_)                                    \
  if (GI_) {                                                                    \
    T3_ISSUE(Asrc, 0, IBUF_, KT2_, 2)                                           \
    T3_ISSUE(Bsrc, 16384, IBUF_, KT2_, 1)                                       \
  }                                                                             \
  T3_READ(BUF_)                                                                 \
  __builtin_amdgcn_s_barrier();                                                 \
  T3_MFMA()                                                                     \
  asm volatile("s_waitcnt vmcnt(" #W_ ")" ::: "memory");                        \
  __builtin_amdgcn_s_barrier();

// K=1024 -> 32 K-tiles of 32. Loop: 10 iters x 3 tiles (static buf), tails.
#define T3_CORE(APTR_, BPTR_)                                                   \
  __shared__ __align__(16) char smem[73728];                                    \
  const int tid = threadIdx.x;                                                  \
  const int lane = tid & 63, wave = tid >> 6;                                   \
  const int col = lane & 15, quad = lane >> 4;                                  \
  const int wrow = wave >> 1, wcol = wave & 1;                                  \
  const int r4 = lane >> 2;                                                     \
  const int gsw = (lane & 3) ^ ((lane >> 3) & 3);                               \
  const int swk = (quad ^ ((col >> 1) & 3)) * 16;                               \
  const char* Asrc = (const char*)(APTR_) + (size_t)(bm + r4) * 2048 + gsw * 16;\
  const char* Bsrc = (const char*)(BPTR_) + (size_t)(bn + r4) * 2048 + gsw * 16;\
  const f32x4 fzero = {0.f, 0.f, 0.f, 0.f};                                     \
  f32x4 acc[4][4];                                                              \
  _Pragma("unroll") for (int i_ = 0; i_ < 4; i_++)                              \
    _Pragma("unroll") for (int j_ = 0; j_ < 4; j_++) acc[i_][j_] = fzero;       \
  s16x8 af[4], bf[4];                                                           \
  T3_ISSUE(Asrc, 0, 0, 0, 2)                                                    \
  T3_ISSUE(Bsrc, 16384, 0, 0, 1)                                                \
  T3_ISSUE(Asrc, 0, 1, 1, 2)                                                    \
  T3_ISSUE(Bsrc, 16384, 1, 1, 1)                                                \
  asm volatile("s_waitcnt vmcnt(3)" ::: "memory");                              \
  __builtin_amdgcn_s_barrier();                                                 \
  _Pragma("clang loop unroll(disable)") for (int it = 0; it < 10; ++it) {       \
    T3_KTILE(0, true, 2, 3 * it + 2, 3)                                         \
    T3_KTILE(1, true, 0, 3 * it + 3, 3)                                         \
    T3_KTILE(2, true, 1, 3 * it + 4, 3)                                         \
  }                                                                             \
  T3_KTILE(0, false, 0, 0, 0)                                                   \
  T3_KTILE(1, false, 0, 0, 0)

// ---------------- fused QKV GEMM + bias + 2D RoPE epilogue ----------------
// Grid 1536 = 8 XCD x (8 bm-strips x 24 bn). bm pinned to XCD (R7-verified:
// FETCH 203->74MB). BN=128 divides 1024 -> seg uniform per block.
__global__ __launch_bounds__(512, 4) void gemm_qkv(const __hip_bfloat16* __restrict__ A,
                                                   const __hip_bfloat16* __restrict__ Wqkv,
                                                   const float* __restrict__ bq,
                                                   const float* __restrict__ bk,
                                                   const float* __restrict__ bv,
                                                   const int* __restrict__ pos,
                                                   __hip_bfloat16* __restrict__ Qb,
                                                   __hip_bfloat16* __restrict__ Kb,
                                                   __hip_bfloat16* __restrict__ Vt) {
  const int xcd = blockIdx.x & 7, s = blockIdx.x >> 3;  // s in [0,192)
  const int bm = (xcd * 8 + (s & 7)) << 8;
  const int bn = (s >> 3) << 7;                         // 24 panels of 128
  T3_CORE(A, Wqkv)

  const int seg = bn >> 10;  // 0=Q 1=K 2=V
  const float* bp = (seg == 0) ? bq : (seg == 1) ? bk : bv;
  const int nbase = (bn & 1023) + wcol * 64;
  float bcol[4];
#pragma unroll
  for (int j = 0; j < 4; j++) bcol[j] = bp[nbase + j * 16 + col];
  if (seg < 2) {
    // sincos table in smem: tab[p*16+f] = {cos,sin} of p * 10000^(-f/8)
    __syncthreads();
    float2* tab = (float2*)smem;
    {
      const int p_ = tid >> 4, f_ = tid & 15;
      const float inv = __expf((float)f_ * -1.1512925464970229f);
      float s_, c_;
      __sincosf((float)p_ * inv, &s_, &c_);
      tab[tid] = make_float2(c_, s_);
    }
    __syncthreads();
    const float SCL = (seg == 0) ? 0.18033688011112043f : 1.0f;  // Q: 0.125*log2(e)
    __hip_bfloat16* P = (seg == 0) ? Qb : Kb;
    const int codd = col & 1;
#pragma unroll
    for (int mi = 0; mi < 4; mi++) {
      const int gr0 = bm + wrow * 64 + mi * 16 + quad * 4;
#pragma unroll
      for (int r = 0; r < 4; r++) {
        const int grow = gr0 + r;
        const int2 pp = *(const int2*)&pos[grow * 2];
        const int iph = pp.x, ipw = pp.y;
#pragma unroll
        for (int ni = 0; ni < 4; ni++) {
          const int f = ((ni & 1) << 3) + (col >> 1);
          const int p_ = (ni >= 2) ? ipw : iph;
          const float2 cs = tab[p_ * 16 + f];
          const float v = acc[mi][ni][r] + bcol[ni];
          const float vp = __shfl_xor(v, 1, 64);
          const float rot = codd ? (v * cs.x + vp * cs.y) : (v * cs.x - vp * cs.y);
          P[(size_t)grow * 1024 + nbase + ni * 16 + col] = __float2bfloat16(rot * SCL);
        }
      }
    }
  } else {
    // V transposed (b,h,d,t): 4 consecutive t per lane -> packed 8B store
#pragma unroll
    for (int mi = 0; mi < 4; mi++) {
      const int gr0 = bm + wrow * 64 + mi * 16 + quad * 4;
      const int bb = gr0 >> 10, tt = gr0 & 1023;
#pragma unroll
      for (int ni = 0; ni < 4; ni++) {
        const int nc = nbase + ni * 16 + col;
        const int hh = nc >> 6, dd = nc & 63;
        u16x4 pk = {f2bu(acc[mi][ni][0] + bcol[ni]), f2bu(acc[mi][ni][1] + bcol[ni]),
                    f2bu(acc[mi][ni][2] + bcol[ni]), f2bu(acc[mi][ni][3] + bcol[ni])};
        *(u16x4*)(Vt + (((size_t)bb * H_ + hh) * DH_ + dd) * T_ + tt) = pk;
      }
    }
  }
}

// ---------------- output-proj GEMM: fp32 out (grid 512 = 8 x 8 x 8) ----------------
__global__ __launch_bounds__(512, 4) void gemm_out(const __hip_bfloat16* __restrict__ A,
                                                   const __hip_bfloat16* __restrict__ Bw,
                                                   const float* __restrict__ bias,
                                                   float* __restrict__ Cout) {
  const int xcd = blockIdx.x & 7, s = blockIdx.x >> 3;  // s in [0,64)
  const int bm = (xcd * 8 + (s & 7)) << 8;
  const int bn = (s >> 3) << 7;                         // 8 panels of 128
  T3_CORE(A, Bw)

  const int nbase = bn + wcol * 64;
  float bcol[4];
#pragma unroll
  for (int j = 0; j < 4; j++) bcol[j] = bias[nbase + j * 16 + col];
#pragma unroll
  for (int mi = 0; mi < 4; mi++) {
    const int gr0 = bm + wrow * 64 + mi * 16 + quad * 4;
#pragma unroll
    for (int ni = 0; ni < 4; ni++) {
      const int gcol = nbase + ni * 16 + col;
#pragma unroll
      for (int r = 0; r < 4; r++)
        Cout[(size_t)(gr0 + r) * 1024 + gcol] = acc[mi][ni][r] + bcol[ni];
    }
  }
}

// ---------------- flash attention (R6-verified, frozen) ----------------
__global__ __launch_bounds__(256, 3) void attn_flash(const __hip_bfloat16* __restrict__ Q,
                                                     const __hip_bfloat16* __restrict__ Kt,
                                                     const __hip_bfloat16* __restrict__ Vt,
                                                     __hip_bfloat16* __restrict__ Oa) {
  __shared__ __align__(16) char QP[128 * 128];   // 16 KB: Q tile then P^T scratch, swizzled
  __shared__ __align__(16) char KV[2][2][8192];  // [buf][K|V][64 rows x 128B, swizzled]

  const int bid = blockIdx.x;          // 2048 = 256 (b,h) x 8 q-tiles
  const int xcd = bid & 7, slot = bid >> 3;
  const int bh = xcd * 32 + (slot >> 3);   // 8 q-tiles + 32 bh share an XCD (L2 reuse)
  const int qt = slot & 7;
  const int b = bh >> 4, h = bh & 15;
  const int tid = threadIdx.x;
  const int lane = tid & 63, wave = tid >> 6;
  const int col = lane & 15, quad = lane >> 4;
  const int r8 = lane >> 3;
  const int gsw = ((lane & 7) ^ r8) * 16;              // global-side XOR pre-swizzle
  const int sw0 = (quad ^ (col & 7)) * 16;             // LDS-side frag-read swizzle
  const int sw1 = ((quad + 4) ^ (col & 7)) * 16;

  const size_t qrow0 = (size_t)b * T_ + qt * 128;

  const char* Kbase = (const char*)(Kt + (size_t)b * T_ * E_ + h * DH_);
  const char* Vbase = (const char*)(Vt + ((size_t)b * H_ + h) * DH_ * (size_t)T_);
#define STAGE_KV(KB_, D_)                                                          \
  {                                                                                \
    _Pragma("unroll") for (int u_ = 0; u_ < 2; ++u_) {                             \
      const int ch_ = u_ * 4 + wave;                                               \
      async_cp16(Kbase + (size_t)((KB_) + ch_ * 8 + r8) * 2048 + gsw,              \
                 &KV[D_][0][ch_ * 1024]);                                          \
      async_cp16(Vbase + (size_t)(ch_ * 8 + r8) * 2048 + (KB_)*2 + gsw,            \
                 &KV[D_][1][ch_ * 1024]);                                          \
    }                                                                              \
  }

  STAGE_KV(0, 0)
#pragma unroll
  for (int cc = 0; cc < 4; ++cc) {
    int c = tid + cc * 256;
    int r = c >> 3, k8 = c & 7;
    const float4* src = (const float4*)((const char*)(Q + (qrow0 + r) * E_ + h * DH_)) + k8;
    *(float4*)(QP + r * 128 + ((k8 ^ (r & 7)) << 4)) = *src;
  }
  __syncthreads();  // drains own vmcnt (cp16 tile0) + lgkm; Q visible

  s16x8 qf[2][2];
#pragma unroll
  for (int g = 0; g < 2; g++) {
    const char* qp = QP + (g * 64 + wave * 16 + col) * 128;
    qf[g][0] = frag8(qp + sw0);
    qf[g][1] = frag8(qp + sw1);
  }
  __syncthreads();

  const f32x4 fzero = {0.f, 0.f, 0.f, 0.f};
  f32x4 o[2][4];
  float lr[2] = {0.f, 0.f};
#pragma unroll
  for (int g = 0; g < 2; g++)
#pragma unroll
    for (int j = 0; j < 4; j++) o[g][j] = fzero;
  char* Pw = QP + wave * 32 * 128;

  for (int kt2 = 0; kt2 < 16; ++kt2) {
    const int d = kt2 & 1;
    if (kt2 < 15) STAGE_KV((kt2 + 1) * 64, d ^ 1)
    s16x8 kf[4][2];
#pragma unroll
    for (int ktile = 0; ktile < 4; ktile++) {
      const char* kp = &KV[d][0][(ktile * 16 + col) * 128];
      kf[ktile][0] = frag8(kp + sw0);
      kf[ktile][1] = frag8(kp + sw1);
    }
    __builtin_amdgcn_s_setprio(1);
#pragma unroll
    for (int g = 0; g < 2; g++) {
#pragma unroll
      for (int ktile = 0; ktile < 4; ktile++) {
        f32x4 dacc = fzero;
        dacc = __builtin_amdgcn_mfma_f32_16x16x32_bf16(kf[ktile][0], qf[g][0], dacc, 0, 0, 0);
        dacc = __builtin_amdgcn_mfma_f32_16x16x32_bf16(kf[ktile][1], qf[g][1], dacc, 0, 0, 0);
        float p0 = fexp2(dacc[0]), p1 = fexp2(dacc[1]), p2 = fexp2(dacc[2]), p3 = fexp2(dacc[3]);
        lr[g] += (p0 + p1) + (p2 + p3);
        u16x4 pk = {f2bu(p0), f2bu(p1), f2bu(p2), f2bu(p3)};
        *(u16x4*)(Pw + (g * 16 + col) * 128 +
                  (((ktile * 2 + (quad >> 1)) ^ (col & 7)) << 4) + ((quad & 1) << 3)) = pk;
      }
    }
    __builtin_amdgcn_s_setprio(0);
    s16x8 vf[4][2];
#pragma unroll
    for (int jm = 0; jm < 4; jm++) {
      const char* vp = &KV[d][1][(jm * 16 + col) * 128];
      vf[jm][0] = frag8(vp + sw0);
      vf[jm][1] = frag8(vp + sw1);
    }
    __builtin_amdgcn_s_setprio(1);
#pragma unroll
    for (int g = 0; g < 2; g++) {
      const char* pp = Pw + (g * 16 + col) * 128;
      s16x8 pf0 = frag8(pp + sw0);
      s16x8 pf1 = frag8(pp + sw1);
#pragma unroll
      for (int jm = 0; jm < 4; jm++) {
        o[g][jm] = __builtin_amdgcn_mfma_f32_16x16x32_bf16(vf[jm][0], pf0, o[g][jm], 0, 0, 0);
        o[g][jm] = __builtin_amdgcn_mfma_f32_16x16x32_bf16(vf[jm][1], pf1, o[g][jm], 0, 0, 0);
      }
    }
    __builtin_amdgcn_s_setprio(0);
    __syncthreads();
  }
#undef STAGE_KV
#pragma unroll
  for (int g = 0; g < 2; g++) {
    lr[g] += __shfl_xor(lr[g], 16, 64);
    lr[g] += __shfl_xor(lr[g], 32, 64);
  }
#pragma unroll
  for (int g = 0; g < 2; g++) {
    float invl = 1.f / lr[g];
    size_t grow = qrow0 + g * 64 + wave * 16 + col;
    char* obase = (char*)(Oa + grow * E_ + h * DH_);
#pragma unroll
    for (int jm = 0; jm < 4; jm++) {
      u16x4 pk = {f2bu(o[g][jm][0] * invl), f2bu(o[g][jm][1] * invl),
                  f2bu(o[g][jm][2] * invl), f2bu(o[g][jm][3] * invl)};
      *(u16x4*)(obase + jm * 32 + quad * 8) = pk;
    }
  }
}

extern "C" void kernel_launch(void* const* d_in, const int* in_sizes, int n_in,
                              void* d_out, int out_size, void* d_ws, size_t ws_size,
                              hipStream_t stream) {
  const float* X   = (const float*)d_in[0];
  const int*   pos = (const int*)d_in[1];
  const float* Wq  = (const float*)d_in[2];
  const float* bq  = (const float*)d_in[3];
  const float* Wk  = (const float*)d_in[4];
  const float* bk  = (const float*)d_in[5];
  const float* Wv  = (const float*)d_in[6];
  const float* bv  = (const float*)d_in[7];
  const float* Wo  = (const float*)d_in[8];
  const float* bo  = (const float*)d_in[9];
  float* out = (float*)d_out;

  char* ws = (char*)d_ws;
  const size_t MB = 1024 * 1024;
  __hip_bfloat16* Xb    = (__hip_bfloat16*)(ws + 0 * MB);    // 32 MB
  __hip_bfloat16* Qb    = (__hip_bfloat16*)(ws + 32 * MB);   // 32 MB
  __hip_bfloat16* Kb    = (__hip_bfloat16*)(ws + 64 * MB);   // 32 MB
  __hip_bfloat16* Vtb   = (__hip_bfloat16*)(ws + 96 * MB);   // 32 MB (b,h,d,t)
  __hip_bfloat16* Wqkvb = (__hip_bfloat16*)(ws + 128 * MB);  // 6 MB (3072x1024)
  __hip_bfloat16* Wob   = (__hip_bfloat16*)(ws + 136 * MB);  // 2 MB
  __hip_bfloat16* Ab    = Xb;  // reuse: X dead after QKV projection

  cast_all<<<20480, 256, 0, stream>>>(X, Wq, Wk, Wv, Wo, Xb, Wqkvb, Wob);

  gemm_qkv<<<1536, 512, 0, stream>>>(Xb, Wqkvb, bq, bk, bv, pos, Qb, Kb, Vtb);

  attn_flash<<<2048, 256, 0, stream>>>(Qb, Kb, Vtb, Ab);

  gemm_out<<<512, 512, 0, stream>>>(Ab, Wob, bo, out);
}